// Round 25
// baseline (120.223 us; speedup 1.0000x reference)
//
#include <hip/hip_runtime.h>
#include <cstdint>

#define L_SEQ 1024
#define NH 16
#define HD 64
#define DMODEL 1024
#define BHS (L_SEQ * HD)   // 65536 elements per (b,h) plane of Q/K/Vt

typedef __bf16 bf16x8 __attribute__((ext_vector_type(8)));
typedef float f32x4 __attribute__((ext_vector_type(4)));
typedef unsigned short u16x8 __attribute__((ext_vector_type(8)));

#define MFMA16(a, b, c) __builtin_amdgcn_mfma_f32_16x16x32_bf16((a), (b), (c), 0, 0, 0)

static __device__ __forceinline__ unsigned short f2b(float f) {
  unsigned int u = __builtin_bit_cast(unsigned int, f);
  u = (u + 0x7FFFu + ((u >> 16) & 1u)) >> 16;
  return (unsigned short)u;
}

static __device__ __forceinline__ float fexp2(float x) {
#if __has_builtin(__builtin_amdgcn_exp2f)
  return __builtin_amdgcn_exp2f(x);
#else
  return exp2f(x);
#endif
}

static __device__ __forceinline__ bf16x8 ld8(const unsigned short* p) {
  return *(const bf16x8*)(p);
}

static __device__ __forceinline__ float bperm(int byteaddr, float v) {
  return __builtin_bit_cast(float,
      __builtin_amdgcn_ds_bpermute(byteaddr, __builtin_bit_cast(int, v)));
}

// async global->LDS, 16B per lane; lds ptr wave-uniform, lane scatters +16B*lane
static __device__ __forceinline__ void gl_lds(const unsigned short* g,
                                              unsigned short* l) {
  auto gp = (const __attribute__((address_space(1))) unsigned int*)((uintptr_t)g);
  auto lp = (__attribute__((address_space(3))) unsigned int*)((uintptr_t)l);
  __builtin_amdgcn_global_load_lds(gp, lp, 16, 0, 0);
}

// ---------------- fused prep: converts + transposes in ONE launch ----------------
__global__ __launch_bounds__(256) void k_prep(
    const float* __restrict__ x,      unsigned short* __restrict__ xb,
    const float* __restrict__ relemb, unsigned short* __restrict__ eb,
    const float* __restrict__ Wqkv,   unsigned short* __restrict__ wtq,
    const float* __restrict__ Wproj,  unsigned short* __restrict__ wtp) {
  const int b = blockIdx.x, tid = threadIdx.x;
  if (b < 4224) {
    const float* src; unsigned short* dst; int i;
    if (b < 4096) { src = x; dst = xb; i = b * 256 + tid; }
    else          { src = relemb; dst = eb; i = (b - 4096) * 256 + tid; }
    const int n4 = (b < 4096) ? 1048576 : 32752;
    if (i < n4) {
      float4 v = *(const float4*)(src + (size_t)i * 4);
      ushort4 o;
      o.x = f2b(v.x); o.y = f2b(v.y); o.z = f2b(v.z); o.w = f2b(v.w);
      *(ushort4*)(dst + (size_t)i * 4) = o;
    }
  } else {
    __shared__ float tile[32][33];
    const float* src; unsigned short* dst; int bx, by, C;
    if (b < 7296) { src = Wqkv; dst = wtq; C = 3072; bx = (b - 4224) % 96; by = (b - 4224) / 96; }
    else          { src = Wproj; dst = wtp; C = 1024; bx = (b - 7296) % 32; by = (b - 7296) / 32; }
    const int R = 1024;
    const int c0 = bx * 32, r0 = by * 32;
    const int tx = tid & 31, ty = tid >> 5;
#pragma unroll
    for (int i = 0; i < 4; ++i)
      tile[ty + i * 8][tx] = src[(size_t)(r0 + ty + i * 8) * C + c0 + tx];
    __syncthreads();
#pragma unroll
    for (int i = 0; i < 4; ++i)
      dst[(size_t)(c0 + ty + i * 8) * R + r0 + tx] = f2b(tile[tx][ty + i * 8]);
  }
}

// ---------------- QKV GEMM: 128x128 tile, BK=64, XOR-swizzled LDS ----------------
// Q third PRE-SCALED by 0.125*log2(e): softmax becomes exp2(s+g), no per-value mul.
__global__ __launch_bounds__(256) void k_gemm_qkv(
    const unsigned short* __restrict__ xb,
    const unsigned short* __restrict__ wt,
    unsigned short* __restrict__ qw,
    unsigned short* __restrict__ kw,
    unsigned short* __restrict__ vtw) {
  __shared__ unsigned short As[128 * 64];
  __shared__ unsigned short Bs[128 * 64];
  const int tid = threadIdx.x;
  const int w = tid >> 6, lane = tid & 63;
  const int wm = w >> 1, wn = w & 1;
  const int lo = lane & 15, hi = lane >> 4;
  const int m0 = blockIdx.y * 128, n0 = blockIdx.x * 128;
  const int srow = lane >> 3, scol = lane & 7;

  f32x4 acc[4][4];
#pragma unroll
  for (int i = 0; i < 4; ++i)
#pragma unroll
    for (int j = 0; j < 4; ++j) acc[i][j] = (f32x4){0.f, 0.f, 0.f, 0.f};

  for (int kt = 0; kt < 16; ++kt) {
    const int k0 = kt * 64;
#pragma unroll
    for (int i = 0; i < 4; ++i) {
      const int slot = w * 4 + i;
      const int r = slot * 8 + srow;
      const int cs = (scol ^ (r & 7)) * 8;
      gl_lds(xb + (size_t)(m0 + r) * 1024 + k0 + cs, &As[slot * 512]);
      gl_lds(wt + (size_t)(n0 + r) * 1024 + k0 + cs, &Bs[slot * 512]);
    }
    __syncthreads();
    bf16x8 af[2][4], bg[2][4];
#pragma unroll
    for (int kk = 0; kk < 2; ++kk)
#pragma unroll
      for (int i = 0; i < 4; ++i) {
        const int ra = wm * 64 + i * 16 + lo;
        const int rb = wn * 64 + i * 16 + lo;
        af[kk][i] = ld8(&As[ra * 64 + (((kk * 4 + hi) ^ (lo & 7)) * 8)]);
        bg[kk][i] = ld8(&Bs[rb * 64 + (((kk * 4 + hi) ^ (lo & 7)) * 8)]);
      }
#pragma unroll
    for (int kk = 0; kk < 2; ++kk)
#pragma unroll
      for (int mf = 0; mf < 4; ++mf)
#pragma unroll
        for (int nf = 0; nf < 4; ++nf)
          acc[mf][nf] = MFMA16(af[kk][mf], bg[kk][nf], acc[mf][nf]);
    __syncthreads();
  }

  const int which = n0 >> 10;
  const float qsc = 0.18033688011112042f;   // 0.125 * log2(e)
#pragma unroll
  for (int mf = 0; mf < 4; ++mf) {
#pragma unroll
    for (int rr = 0; rr < 4; ++rr) {
      const int row = m0 + wm * 64 + mf * 16 + hi * 4 + rr;
      const int bb = row >> 10, ll = row & 1023;
#pragma unroll
      for (int nf = 0; nf < 4; ++nf) {
        const int col = n0 + wn * 64 + nf * 16 + lo;
        const int hc = col & 1023;
        const int hh = hc >> 6, dd = hc & 63;
        const float av = (which == 0) ? acc[mf][nf][rr] * qsc : acc[mf][nf][rr];
        const unsigned short val = f2b(av);
        const size_t bh = (size_t)(bb * NH + hh);
        if (which == 0)      qw[bh * BHS + ll * HD + dd] = val;
        else if (which == 1) kw[bh * BHS + ll * HD + dd] = val;
        else                 vtw[bh * BHS + dd * L_SEQ + ll] = val;
      }
    }
  }
}

// ---------------- fused attention: 2-wave blocks, KVBLK=64, 4 blocks/CU ----------------
// Block = 2 waves x 32 q-rows (2 subtiles each) = 64 q-rows; grid 1024 = 4
// independent blocks/CU (same 8 waves/CU as R24 but 4 unsynced groups, 2-wave
// barriers). K/V dbuf-staged via gl_lds; E direct; exp2 softmax + cvt_pk (R24).
__global__ __launch_bounds__(128, 2) void k_attn(
    const unsigned short* __restrict__ qw,
    const unsigned short* __restrict__ kw,
    const unsigned short* __restrict__ vtw,
    const unsigned short* __restrict__ ew,   // [2047][64] bf16
    unsigned short* __restrict__ ow) {
  __shared__ unsigned short Kb[2][4096];     //  8KB x2: K tile [64 rows][64]
  __shared__ unsigned short Vb[2][4096];     //  8KB x2: Vt tile [64 d][64 j]
  __shared__ unsigned short Ps[2][16][72];   // per-wave P tile, reused by subtiles
  const int tid = threadIdx.x;
  const int w = tid >> 6, lane = tid & 63;   // w in 0..1
  const int lo = lane & 15, hi = lane >> 4;
  const int cw = lo & 7;
  // XCD swizzle: nwg=1024, chunk 128/XCD
  const int lbid = (blockIdx.x & 7) * 128 + (blockIdx.x >> 3);
  const int bh = lbid >> 4, qb = lbid & 15;
  const int q0 = qb * 64;
  const int l0w = q0 + w * 32;               // this wave's 32 q-rows
  const int bb = bh >> 4, hh = bh & 15;

  bf16x8 aQ[2][2];
#pragma unroll
  for (int s = 0; s < 2; ++s) {
    const unsigned short* qbase = qw + (size_t)bh * BHS + (l0w + s * 16 + lo) * HD;
    aQ[s][0] = ld8(qbase + hi * 8);
    aQ[s][1] = ld8(qbase + 32 + hi * 8);
  }

  const unsigned short* kbase = kw + (size_t)bh * BHS;
  const unsigned short* vbase = vtw + (size_t)bh * BHS;

  const u16x8 one_u = {0x3F80, 0x3F80, 0x3F80, 0x3F80,
                       0x3F80, 0x3F80, 0x3F80, 0x3F80};
  const bf16x8 onesf = __builtin_bit_cast(bf16x8, one_u);

  int gaddr[4];
  bool gpred[4];
#pragma unroll
  for (int r = 0; r < 4; ++r) {
    const int rho = hi * 4 + r;
    const int t = lo + 15 - rho;
    gaddr[r] = (hi * 16 + (t & 15)) * 4;
    gpred[r] = t >= 16;
  }

  // stage 64-key tile tt into buffer nxt: 4 K-slots + 4 V-slots per wave
  auto stage = [&](int nxt, int tt) {
    const unsigned short* kt = kbase + (size_t)tt * 64 * 64;   // contiguous 8KB
    const unsigned short* vt = vbase + tt * 64;                // row stride 1024
#pragma unroll
    for (int i = 0; i < 4; ++i) {
      const int n = (w * 4 + i) * 64 + lane;
      const int r = n >> 3, c = n & 7;                          // r: key 0..63
      gl_lds(kt + r * 64 + ((c ^ (r & 7)) * 8), &Kb[nxt][(w * 4 + i) * 512]);
    }
#pragma unroll
    for (int i = 0; i < 4; ++i) {
      const int n = (w * 4 + i) * 64 + lane;
      const int d = n >> 3, c = n & 7;                          // d: 0..63
      gl_lds(vt + (size_t)d * 1024 + ((c ^ (d & 7)) * 8), &Vb[nxt][(w * 4 + i) * 512]);
    }
  };

  f32x4 acc_o[2][4];
  f32x4 acc_l[2];
#pragma unroll
  for (int s = 0; s < 2; ++s) {
    acc_l[s] = (f32x4){0.f, 0.f, 0.f, 0.f};
#pragma unroll
    for (int d = 0; d < 4; ++d) acc_o[s][d] = (f32x4){0.f, 0.f, 0.f, 0.f};
  }

  stage(0, 0);
  __syncthreads();

#pragma unroll 1
  for (int t = 0; t < 16; ++t) {
    const int cur = t & 1;
    if (t < 15) stage(cur ^ 1, t + 1);

    // ---- E window (6 shared fragments) ----
    const int xbase = t * 64 - l0w + 992;   // >= 0 always (t=0, l0w<=992)
    bf16x8 ef[6][2];
#pragma unroll
    for (int f = 0; f < 6; ++f) {
      int er = xbase + f * 16 + lo;
      er = er > 2046 ? 2046 : er;           // clamp: feeds unused entries only
      const unsigned short* erow = ew + (size_t)er * HD + hi * 8;
      ef[f][0] = ld8(erow);
      ef[f][1] = ld8(erow + 32);
    }

    // ---- K fragments (read once, both subtiles) ----
    bf16x8 kf[4][2];
#pragma unroll
    for (int nf = 0; nf < 4; ++nf) {
      const unsigned short* kr = &Kb[cur][(nf * 16 + lo) * 64];
      kf[nf][0] = ld8(kr + ((hi ^ cw) * 8));
      kf[nf][1] = ld8(kr + (((4 + hi) ^ cw) * 8));
    }

    // ---- content scores, both subtiles ----
    f32x4 acc_s[2][4];
    __builtin_amdgcn_s_setprio(1);
#pragma unroll
    for (int s = 0; s < 2; ++s)
#pragma unroll
      for (int nf = 0; nf < 4; ++nf) {
        f32x4 c = (f32x4){0.f, 0.f, 0.f, 0.f};
        c = MFMA16(aQ[s][0], kf[nf][0], c);
        c = MFMA16(aQ[s][1], kf[nf][1], c);
        acc_s[s][nf] = c;
      }
    __builtin_amdgcn_s_setprio(0);

    // ---- pos scores (s=0 -> ef[1..5], s=1 -> ef[0..4]) + bperm rotate ----
    f32x4 G[2][5];
#pragma unroll
    for (int s = 0; s < 2; ++s) {
      const int fb = 1 - s;
#pragma unroll
      for (int gf = 0; gf < 5; ++gf) {
        f32x4 g = (f32x4){0.f, 0.f, 0.f, 0.f};
        g = MFMA16(aQ[s][0], ef[gf + fb][0], g);
        g = MFMA16(aQ[s][1], ef[gf + fb][1], g);
        G[s][gf] = g;
      }
    }
#pragma unroll
    for (int s = 0; s < 2; ++s)
#pragma unroll
      for (int gf = 0; gf < 5; ++gf)
#pragma unroll
        for (int r = 0; r < 4; ++r)
          G[s][gf][r] = bperm(gaddr[r], G[s][gf][r]);

    // ---- V fragments (read once, both subtiles) ----
    bf16x8 vf[4][2];
#pragma unroll
    for (int df = 0; df < 4; ++df) {
      const unsigned short* vr = &Vb[cur][(df * 16 + lo) * 64];
      vf[df][0] = ld8(vr + ((hi ^ cw) * 8));
      vf[df][1] = ld8(vr + (((4 + hi) ^ cw) * 8));
    }

    // ---- per-subtile: exp2 softmax -> cvt_pk -> Ps -> l, PV ----
#pragma unroll
    for (int s = 0; s < 2; ++s) {
#pragma unroll
      for (int nf = 0; nf < 4; ++nf)
#pragma unroll
        for (int rp = 0; rp < 2; ++rp) {
          const int r0 = rp * 2, r1 = r0 + 1;
          const float g0 = gpred[r0] ? G[s][nf + 1][r0] : G[s][nf][r0];
          const float g1 = gpred[r1] ? G[s][nf + 1][r1] : G[s][nf][r1];
          const float e0 = fexp2(acc_s[s][nf][r0] + g0);
          const float e1 = fexp2(acc_s[s][nf][r1] + g1);
          unsigned int pk;
          asm("v_cvt_pk_bf16_f32 %0, %1, %2" : "=v"(pk) : "v"(e0), "v"(e1));
          Ps[w][hi * 4 + r0][nf * 16 + lo] = (unsigned short)pk;
          Ps[w][hi * 4 + r1][nf * 16 + lo] = (unsigned short)(pk >> 16);
        }
      const bf16x8 aP0 = ld8(&Ps[w][lo][hi * 8]);
      const bf16x8 aP1 = ld8(&Ps[w][lo][32 + hi * 8]);
      acc_l[s] = MFMA16(aP0, onesf, acc_l[s]);
      acc_l[s] = MFMA16(aP1, onesf, acc_l[s]);
      __builtin_amdgcn_s_setprio(1);
#pragma unroll
      for (int df = 0; df < 4; ++df) {
        acc_o[s][df] = MFMA16(aP0, vf[df][0], acc_o[s][df]);
        acc_o[s][df] = MFMA16(aP1, vf[df][1], acc_o[s][df]);
      }
      __builtin_amdgcn_s_setprio(0);
    }

    __syncthreads();   // 2-wave barrier: drains staging + protects buffer swap
  }

  // epilogue: O / l, write [b, l, h*64+d] bf16
#pragma unroll
  for (int s = 0; s < 2; ++s)
#pragma unroll
    for (int r = 0; r < 4; ++r) {
      const int l = l0w + s * 16 + hi * 4 + r;
      const float inv = 1.f / acc_l[s][r];
      unsigned short* orow = ow + ((size_t)(bb * L_SEQ + l)) * DMODEL + hh * HD;
#pragma unroll
      for (int df = 0; df < 4; ++df)
        orow[df * 16 + lo] = f2b(acc_o[s][df][r] * inv);
    }
}

// ---------------- output projection: 128x64 tile, BK=64 — 512 blocks = 2/CU ----------------
__global__ __launch_bounds__(256) void k_gemm_proj(
    const unsigned short* __restrict__ ob,
    const unsigned short* __restrict__ wt,
    const float* __restrict__ bias,
    float* __restrict__ out) {
  __shared__ unsigned short As[128 * 64];   // 16KB: A tile [128 rows][64]
  __shared__ unsigned short Bs[64 * 64];    //  8KB: B tile [64 rows][64]
  const int tid = threadIdx.x;
  const int w = tid >> 6, lane = tid & 63;
  const int wm = w >> 1, wn = w & 1;
  const int lo = lane & 15, hi = lane >> 4;
  const int m0 = blockIdx.y * 128, n0 = blockIdx.x * 64;
  const int srow = lane >> 3, scol = lane & 7;

  f32x4 acc[4][2];
#pragma unroll
  for (int i = 0; i < 4; ++i)
#pragma unroll
    for (int j = 0; j < 2; ++j) acc[i][j] = (f32x4){0.f, 0.f, 0.f, 0.f};

  for (int kt = 0; kt < 16; ++kt) {
    const int k0 = kt * 64;
#pragma unroll
    for (int i = 0; i < 4; ++i) {
      const int slot = w * 4 + i;           // A: 16 slots x 8 rows
      const int r = slot * 8 + srow;
      const int cs = (scol ^ (r & 7)) * 8;
      gl_lds(ob + (size_t)(m0 + r) * 1024 + k0 + cs, &As[slot * 512]);
    }
#pragma unroll
    for (int i = 0; i < 2; ++i) {
      const int slot = w * 2 + i;           // B: 8 slots x 8 rows
      const int r = slot * 8 + srow;
      const int cs = (scol ^ (r & 7)) * 8;
      gl_lds(wt + (size_t)(n0 + r) * 1024 + k0 + cs, &Bs[slot * 512]);
    }
    __syncthreads();
    bf16x8 af[2][4], bg[2][2];
#pragma unroll
    for (int kk = 0; kk < 2; ++kk) {
#pragma unroll
      for (int i = 0; i < 4; ++i) {
        const int ra = wm * 64 + i * 16 + lo;
        af[kk][i] = ld8(&As[ra * 64 + (((kk * 4 + hi) ^ (lo & 7)) * 8)]);
      }
#pragma unroll
      for (int j = 0; j < 2; ++j) {
        const int rb = wn * 32 + j * 16 + lo;
        bg[kk][j] = ld8(&Bs[rb * 64 + (((kk * 4 + hi) ^ (lo & 7)) * 8)]);
      }
    }
#pragma unroll
    for (int kk = 0; kk < 2; ++kk)
#pragma unroll
      for (int mf = 0; mf < 4; ++mf)
#pragma unroll
        for (int nf = 0; nf < 2; ++nf)
          acc[mf][nf] = MFMA16(af[kk][mf], bg[kk][nf], acc[mf][nf]);
    __syncthreads();
  }

#pragma unroll
  for (int mf = 0; mf < 4; ++mf) {
#pragma unroll
    for (int rr = 0; rr < 4; ++rr) {
      const int row = m0 + wm * 64 + mf * 16 + hi * 4 + rr;
#pragma unroll
      for (int nf = 0; nf < 2; ++nf) {
        const int col = n0 + wn * 32 + nf * 16 + lo;
        out[(size_t)row * 1024 + col] = acc[mf][nf][rr] + bias[col];
      }
    }
  }
}

extern "C" void kernel_launch(void* const* d_in, const int* in_sizes, int n_in,
                              void* d_out, int out_size, void* d_ws, size_t ws_size,
                              hipStream_t stream) {
  const float* x      = (const float*)d_in[0];
  const float* Wqkv   = (const float*)d_in[1];
  const float* Wproj  = (const float*)d_in[2];
  const float* bproj  = (const float*)d_in[3];
  const float* relemb = (const float*)d_in[4];
  float* out = (float*)d_out;

  char* ws = (char*)d_ws;
  size_t off = 0;
  auto alloc = [&](size_t bytes) -> unsigned short* {
    unsigned short* p = (unsigned short*)(ws + off);
    off += (bytes + 255) & ~(size_t)255;
    return p;
  };
  unsigned short* xb  = alloc((size_t)4096 * 1024 * 2);
  unsigned short* wtq = alloc((size_t)3072 * 1024 * 2);
  unsigned short* wtp = alloc((size_t)1024 * 1024 * 2);
  unsigned short* eb  = alloc((size_t)2047 * 64 * 2);
  unsigned short* qw_ = alloc((size_t)64 * BHS * 2);
  unsigned short* kw_ = alloc((size_t)64 * BHS * 2);
  unsigned short* vtw = alloc((size_t)64 * BHS * 2);
  unsigned short* ow  = alloc((size_t)4096 * 1024 * 2);

  k_prep<<<8320, 256, 0, stream>>>(x, xb, relemb, eb, Wqkv, wtq, Wproj, wtp);
  k_gemm_qkv<<<dim3(24, 32), 256, 0, stream>>>(xb, wtq, qw_, kw_, vtw);
  k_attn<<<1024, 128, 0, stream>>>(qw_, kw_, vtw, eb, ow);
  k_gemm_proj<<<dim3(16, 32), 256, 0, stream>>>(ow, wtp, bproj, out);
}

// Round 26
// 116.116 us; speedup vs baseline: 1.0354x; 1.0354x over previous
//
#include <hip/hip_runtime.h>
#include <cstdint>

#define L_SEQ 1024
#define NH 16
#define HD 64
#define DMODEL 1024
#define BHS (L_SEQ * HD)   // 65536 elements per (b,h) plane of Q/K/Vt

typedef __bf16 bf16x8 __attribute__((ext_vector_type(8)));
typedef float f32x4 __attribute__((ext_vector_type(4)));
typedef unsigned short u16x8 __attribute__((ext_vector_type(8)));

#define MFMA16(a, b, c) __builtin_amdgcn_mfma_f32_16x16x32_bf16((a), (b), (c), 0, 0, 0)

static __device__ __forceinline__ unsigned short f2b(float f) {
  unsigned int u = __builtin_bit_cast(unsigned int, f);
  u = (u + 0x7FFFu + ((u >> 16) & 1u)) >> 16;
  return (unsigned short)u;
}

static __device__ __forceinline__ float fexp2(float x) {
#if __has_builtin(__builtin_amdgcn_exp2f)
  return __builtin_amdgcn_exp2f(x);
#else
  return exp2f(x);
#endif
}

static __device__ __forceinline__ bf16x8 ld8(const unsigned short* p) {
  return *(const bf16x8*)(p);
}

static __device__ __forceinline__ float bperm(int byteaddr, float v) {
  return __builtin_bit_cast(float,
      __builtin_amdgcn_ds_bpermute(byteaddr, __builtin_bit_cast(int, v)));
}

// async global->LDS, 16B per lane; lds ptr wave-uniform, lane scatters +16B*lane
static __device__ __forceinline__ void gl_lds(const unsigned short* g,
                                              unsigned short* l) {
  auto gp = (const __attribute__((address_space(1))) unsigned int*)((uintptr_t)g);
  auto lp = (__attribute__((address_space(3))) unsigned int*)((uintptr_t)l);
  __builtin_amdgcn_global_load_lds(gp, lp, 16, 0, 0);
}

// ---------------- fused prep: converts + transposes in ONE launch ----------------
__global__ __launch_bounds__(256) void k_prep(
    const float* __restrict__ x,      unsigned short* __restrict__ xb,
    const float* __restrict__ relemb, unsigned short* __restrict__ eb,
    const float* __restrict__ Wqkv,   unsigned short* __restrict__ wtq,
    const float* __restrict__ Wproj,  unsigned short* __restrict__ wtp) {
  const int b = blockIdx.x, tid = threadIdx.x;
  if (b < 4224) {
    const float* src; unsigned short* dst; int i;
    if (b < 4096) { src = x; dst = xb; i = b * 256 + tid; }
    else          { src = relemb; dst = eb; i = (b - 4096) * 256 + tid; }
    const int n4 = (b < 4096) ? 1048576 : 32752;
    if (i < n4) {
      float4 v = *(const float4*)(src + (size_t)i * 4);
      ushort4 o;
      o.x = f2b(v.x); o.y = f2b(v.y); o.z = f2b(v.z); o.w = f2b(v.w);
      *(ushort4*)(dst + (size_t)i * 4) = o;
    }
  } else {
    __shared__ float tile[32][33];
    const float* src; unsigned short* dst; int bx, by, C;
    if (b < 7296) { src = Wqkv; dst = wtq; C = 3072; bx = (b - 4224) % 96; by = (b - 4224) / 96; }
    else          { src = Wproj; dst = wtp; C = 1024; bx = (b - 7296) % 32; by = (b - 7296) / 32; }
    const int R = 1024;
    const int c0 = bx * 32, r0 = by * 32;
    const int tx = tid & 31, ty = tid >> 5;
#pragma unroll
    for (int i = 0; i < 4; ++i)
      tile[ty + i * 8][tx] = src[(size_t)(r0 + ty + i * 8) * C + c0 + tx];
    __syncthreads();
#pragma unroll
    for (int i = 0; i < 4; ++i)
      dst[(size_t)(c0 + ty + i * 8) * R + r0 + tx] = f2b(tile[tx][ty + i * 8]);
  }
}

// ---------------- QKV GEMM: 128x128 tile, BK=64, XOR-swizzled LDS ----------------
// Q third is PRE-SCALED by 0.125*log2(e) so attention softmax is exp2(s+g)
// with zero per-value multiplies (scale propagates linearly through qk and qE).
__global__ __launch_bounds__(256) void k_gemm_qkv(
    const unsigned short* __restrict__ xb,
    const unsigned short* __restrict__ wt,
    unsigned short* __restrict__ qw,
    unsigned short* __restrict__ kw,
    unsigned short* __restrict__ vtw) {
  __shared__ unsigned short As[128 * 64];
  __shared__ unsigned short Bs[128 * 64];
  const int tid = threadIdx.x;
  const int w = tid >> 6, lane = tid & 63;
  const int wm = w >> 1, wn = w & 1;
  const int lo = lane & 15, hi = lane >> 4;
  const int m0 = blockIdx.y * 128, n0 = blockIdx.x * 128;
  const int srow = lane >> 3, scol = lane & 7;

  f32x4 acc[4][4];
#pragma unroll
  for (int i = 0; i < 4; ++i)
#pragma unroll
    for (int j = 0; j < 4; ++j) acc[i][j] = (f32x4){0.f, 0.f, 0.f, 0.f};

  for (int kt = 0; kt < 16; ++kt) {
    const int k0 = kt * 64;
#pragma unroll
    for (int i = 0; i < 4; ++i) {
      const int slot = w * 4 + i;
      const int r = slot * 8 + srow;
      const int cs = (scol ^ (r & 7)) * 8;
      gl_lds(xb + (size_t)(m0 + r) * 1024 + k0 + cs, &As[slot * 512]);
      gl_lds(wt + (size_t)(n0 + r) * 1024 + k0 + cs, &Bs[slot * 512]);
    }
    __syncthreads();
    bf16x8 af[2][4], bg[2][4];
#pragma unroll
    for (int kk = 0; kk < 2; ++kk)
#pragma unroll
      for (int i = 0; i < 4; ++i) {
        const int ra = wm * 64 + i * 16 + lo;
        const int rb = wn * 64 + i * 16 + lo;
        af[kk][i] = ld8(&As[ra * 64 + (((kk * 4 + hi) ^ (lo & 7)) * 8)]);
        bg[kk][i] = ld8(&Bs[rb * 64 + (((kk * 4 + hi) ^ (lo & 7)) * 8)]);
      }
#pragma unroll
    for (int kk = 0; kk < 2; ++kk)
#pragma unroll
      for (int mf = 0; mf < 4; ++mf)
#pragma unroll
        for (int nf = 0; nf < 4; ++nf)
          acc[mf][nf] = MFMA16(af[kk][mf], bg[kk][nf], acc[mf][nf]);
    __syncthreads();
  }

  const int which = n0 >> 10;
  const float qsc = 0.18033688011112042f;   // 0.125 * log2(e)
#pragma unroll
  for (int mf = 0; mf < 4; ++mf) {
#pragma unroll
    for (int rr = 0; rr < 4; ++rr) {
      const int row = m0 + wm * 64 + mf * 16 + hi * 4 + rr;
      const int bb = row >> 10, ll = row & 1023;
#pragma unroll
      for (int nf = 0; nf < 4; ++nf) {
        const int col = n0 + wn * 64 + nf * 16 + lo;
        const int hc = col & 1023;
        const int hh = hc >> 6, dd = hc & 63;
        const float av = (which == 0) ? acc[mf][nf][rr] * qsc : acc[mf][nf][rr];
        const unsigned short val = f2b(av);
        const size_t bh = (size_t)(bb * NH + hh);
        if (which == 0)      qw[bh * BHS + ll * HD + dd] = val;
        else if (which == 1) kw[bh * BHS + ll * HD + dd] = val;
        else                 vtw[bh * BHS + dd * L_SEQ + ll] = val;
      }
    }
  }
}

// ---------------- fused attention: R13 structure + setprio + VALU diet ----------------
// KVBLK=128 double-tile, 2 passes + 1 barrier/iter, 4 waves x 2 subtiles.
// Q pre-scaled at QKV: softmax = exp2(acc+g) (single v_exp); P->bf16 via
// v_cvt_pk_bf16_f32 (HW RNE = f2b). setprio load-bearing (R20: +11% without).
// 2 blocks/CU x 2 subtiles/wave is the verified saddle point (R9/R22/R25).
__global__ __launch_bounds__(256, 2) void k_attn(
    const unsigned short* __restrict__ qw,
    const unsigned short* __restrict__ kw,
    const unsigned short* __restrict__ vtw,
    const unsigned short* __restrict__ ew,   // [2047][64] bf16
    unsigned short* __restrict__ ow) {
  __shared__ unsigned short Kb[2][8192];     // 16KB x2: K double-tile [128 rows][64]
  __shared__ unsigned short Vb[2][8192];     // 16KB x2: V [2 halves][64 d][64 j]
  __shared__ unsigned short Ps[4][16][72];   // per-wave P tile, reused by subtiles
  const int tid = threadIdx.x;
  const int w = tid >> 6, lane = tid & 63;
  const int lo = lane & 15, hi = lane >> 4;
  const int cw = lo & 7;
  const int lbid = (blockIdx.x & 7) * 64 + (blockIdx.x >> 3);
  const int bh = lbid >> 3, qb = lbid & 7;
  const int q0 = qb * 128;
  const int l0w = q0 + w * 32;
  const int bb = bh >> 4, hh = bh & 15;

  bf16x8 aQ[2][2];
#pragma unroll
  for (int s = 0; s < 2; ++s) {
    const unsigned short* qbase = qw + (size_t)bh * BHS + (l0w + s * 16 + lo) * HD;
    aQ[s][0] = ld8(qbase + hi * 8);
    aQ[s][1] = ld8(qbase + 32 + hi * 8);
  }

  const unsigned short* kbase = kw + (size_t)bh * BHS;
  const unsigned short* vbase = vtw + (size_t)bh * BHS;

  const u16x8 one_u = {0x3F80, 0x3F80, 0x3F80, 0x3F80,
                       0x3F80, 0x3F80, 0x3F80, 0x3F80};
  const bf16x8 onesf = __builtin_bit_cast(bf16x8, one_u);

  int gaddr[4];
  bool gpred[4];
#pragma unroll
  for (int r = 0; r < 4; ++r) {
    const int rho = hi * 4 + r;
    const int t = lo + 15 - rho;
    gaddr[r] = (hi * 16 + (t & 15)) * 4;
    gpred[r] = t >= 16;
  }

  // stage double-tile it2 (128 keys): K 16KB + V 16KB, 8 gl_lds per wave
  auto stage = [&](int nxt, int it2) {
    const unsigned short* kt = kbase + (size_t)it2 * 128 * 64;   // contiguous 16KB
    const unsigned short* vt = vbase + it2 * 128;                // row stride 1024
#pragma unroll
    for (int i = 0; i < 4; ++i) {
      const int n = (w * 4 + i) * 64 + lane;
      const int r = n >> 3, c = n & 7;                            // r: key 0..127
      gl_lds(kt + r * 64 + ((c ^ (r & 7)) * 8), &Kb[nxt][(w * 4 + i) * 512]);
    }
#pragma unroll
    for (int i = 0; i < 4; ++i) {
      const int n = (w * 4 + i) * 64 + lane;
      const int m = n >> 3, c = n & 7;                            // m = h*64 + d
      const int hhalf = m >> 6, dd = m & 63;
      gl_lds(vt + (size_t)dd * 1024 + hhalf * 64 + ((c ^ (m & 7)) * 8),
             &Vb[nxt][(w * 4 + i) * 512]);
    }
  };

  f32x4 acc_o[2][4];
  f32x4 acc_l[2];
#pragma unroll
  for (int s = 0; s < 2; ++s) {
    acc_l[s] = (f32x4){0.f, 0.f, 0.f, 0.f};
#pragma unroll
    for (int d = 0; d < 4; ++d) acc_o[s][d] = (f32x4){0.f, 0.f, 0.f, 0.f};
  }

  stage(0, 0);
  __syncthreads();

  // one 64-key pass: half p of buffer cur, absolute 64-key tile index tAbs
  auto pass = [&](int cur, int p, int tAbs) {
    // ---- E window (6 shared fragments) ----
    const int xbase = tAbs * 64 - l0w + 992;   // >= 0 always
    bf16x8 ef[6][2];
#pragma unroll
    for (int f = 0; f < 6; ++f) {
      int er = xbase + f * 16 + lo;
      er = er > 2046 ? 2046 : er;              // clamp: feeds unused entries only
      const unsigned short* erow = ew + (size_t)er * HD + hi * 8;
      ef[f][0] = ld8(erow);
      ef[f][1] = ld8(erow + 32);
    }

    // ---- K fragments from Kb[cur] rows p*64.. (read once, both subtiles) ----
    bf16x8 kf[4][2];
#pragma unroll
    for (int nf = 0; nf < 4; ++nf) {
      const unsigned short* kr = &Kb[cur][(p * 64 + nf * 16 + lo) * 64];
      kf[nf][0] = ld8(kr + ((hi ^ cw) * 8));
      kf[nf][1] = ld8(kr + (((4 + hi) ^ cw) * 8));
    }

    // ---- content scores, both subtiles ----
    f32x4 acc_s[2][4];
    __builtin_amdgcn_s_setprio(1);
#pragma unroll
    for (int s = 0; s < 2; ++s)
#pragma unroll
      for (int nf = 0; nf < 4; ++nf) {
        f32x4 c = (f32x4){0.f, 0.f, 0.f, 0.f};
        c = MFMA16(aQ[s][0], kf[nf][0], c);
        c = MFMA16(aQ[s][1], kf[nf][1], c);
        acc_s[s][nf] = c;
      }
    __builtin_amdgcn_s_setprio(0);

    // ---- pos scores (s=0 -> ef[1..5], s=1 -> ef[0..4]) + bperm rotate ----
    f32x4 G[2][5];
#pragma unroll
    for (int s = 0; s < 2; ++s) {
      const int fb = 1 - s;
#pragma unroll
      for (int gf = 0; gf < 5; ++gf) {
        f32x4 g = (f32x4){0.f, 0.f, 0.f, 0.f};
        g = MFMA16(aQ[s][0], ef[gf + fb][0], g);
        g = MFMA16(aQ[s][1], ef[gf + fb][1], g);
        G[s][gf] = g;
      }
    }
#pragma unroll
    for (int s = 0; s < 2; ++s)
#pragma unroll
      for (int gf = 0; gf < 5; ++gf)
#pragma unroll
        for (int r = 0; r < 4; ++r)
          G[s][gf][r] = bperm(gaddr[r], G[s][gf][r]);

    // ---- V fragments from Vb[cur] half p (read once, both subtiles) ----
    bf16x8 vf[4][2];
#pragma unroll
    for (int df = 0; df < 4; ++df) {
      const unsigned short* vr = &Vb[cur][(p * 64 + df * 16 + lo) * 64];
      vf[df][0] = ld8(vr + ((hi ^ cw) * 8));
      vf[df][1] = ld8(vr + (((4 + hi) ^ cw) * 8));
    }

    // ---- per-subtile: exp2 softmax -> cvt_pk -> Ps -> l, PV ----
#pragma unroll
    for (int s = 0; s < 2; ++s) {
#pragma unroll
      for (int nf = 0; nf < 4; ++nf)
#pragma unroll
        for (int rp = 0; rp < 2; ++rp) {
          const int r0 = rp * 2, r1 = r0 + 1;
          const float g0 = gpred[r0] ? G[s][nf + 1][r0] : G[s][nf][r0];
          const float g1 = gpred[r1] ? G[s][nf + 1][r1] : G[s][nf][r1];
          const float e0 = fexp2(acc_s[s][nf][r0] + g0);
          const float e1 = fexp2(acc_s[s][nf][r1] + g1);
          unsigned int pk;
          asm("v_cvt_pk_bf16_f32 %0, %1, %2" : "=v"(pk) : "v"(e0), "v"(e1));
          Ps[w][hi * 4 + r0][nf * 16 + lo] = (unsigned short)pk;
          Ps[w][hi * 4 + r1][nf * 16 + lo] = (unsigned short)(pk >> 16);
        }
      const bf16x8 aP0 = ld8(&Ps[w][lo][hi * 8]);
      const bf16x8 aP1 = ld8(&Ps[w][lo][32 + hi * 8]);
      acc_l[s] = MFMA16(aP0, onesf, acc_l[s]);
      acc_l[s] = MFMA16(aP1, onesf, acc_l[s]);
      __builtin_amdgcn_s_setprio(1);
#pragma unroll
      for (int df = 0; df < 4; ++df) {
        acc_o[s][df] = MFMA16(aP0, vf[df][0], acc_o[s][df]);
        acc_o[s][df] = MFMA16(aP1, vf[df][1], acc_o[s][df]);
      }
      __builtin_amdgcn_s_setprio(0);
    }
  };

#pragma unroll 1
  for (int it = 0; it < 8; ++it) {
    const int cur = it & 1;
    pass(cur, 0, 2 * it);                 // keys it*128 .. +63
    if (it < 7) stage(cur ^ 1, it + 1);   // issue next staging; drains at barrier
    pass(cur, 1, 2 * it + 1);             // keys it*128+64 .. +127
    __syncthreads();                      // ONE barrier per 128 keys
  }

  // epilogue: O / l, write [b, l, h*64+d] bf16
#pragma unroll
  for (int s = 0; s < 2; ++s)
#pragma unroll
    for (int r = 0; r < 4; ++r) {
      const int l = l0w + s * 16 + hi * 4 + r;
      const float inv = 1.f / acc_l[s][r];
      unsigned short* orow = ow + ((size_t)(bb * L_SEQ + l)) * DMODEL + hh * HD;
#pragma unroll
      for (int df = 0; df < 4; ++df)
        orow[df * 16 + lo] = f2b(acc_o[s][df][r] * inv);
    }
}

// ---------------- output projection: 128x64 tile, BK=64 — 512 blocks = 2/CU ----------------
__global__ __launch_bounds__(256) void k_gemm_proj(
    const unsigned short* __restrict__ ob,
    const unsigned short* __restrict__ wt,
    const float* __restrict__ bias,
    float* __restrict__ out) {
  __shared__ unsigned short As[128 * 64];   // 16KB: A tile [128 rows][64]
  __shared__ unsigned short Bs[64 * 64];    //  8KB: B tile [64 rows][64]
  const int tid = threadIdx.x;
  const int w = tid >> 6, lane = tid & 63;
  const int wm = w >> 1, wn = w & 1;
  const int lo = lane & 15, hi = lane >> 4;
  const int m0 = blockIdx.y * 128, n0 = blockIdx.x * 64;
  const int srow = lane >> 3, scol = lane & 7;

  f32x4 acc[4][2];
#pragma unroll
  for (int i = 0; i < 4; ++i)
#pragma unroll
    for (int j = 0; j < 2; ++j) acc[i][j] = (f32x4){0.f, 0.f, 0.f, 0.f};

  for (int kt = 0; kt < 16; ++kt) {
    const int k0 = kt * 64;
#pragma unroll
    for (int i = 0; i < 4; ++i) {
      const int slot = w * 4 + i;           // A: 16 slots x 8 rows
      const int r = slot * 8 + srow;
      const int cs = (scol ^ (r & 7)) * 8;
      gl_lds(ob + (size_t)(m0 + r) * 1024 + k0 + cs, &As[slot * 512]);
    }
#pragma unroll
    for (int i = 0; i < 2; ++i) {
      const int slot = w * 2 + i;           // B: 8 slots x 8 rows
      const int r = slot * 8 + srow;
      const int cs = (scol ^ (r & 7)) * 8;
      gl_lds(wt + (size_t)(n0 + r) * 1024 + k0 + cs, &Bs[slot * 512]);
    }
    __syncthreads();
    bf16x8 af[2][4], bg[2][2];
#pragma unroll
    for (int kk = 0; kk < 2; ++kk) {
#pragma unroll
      for (int i = 0; i < 4; ++i) {
        const int ra = wm * 64 + i * 16 + lo;
        af[kk][i] = ld8(&As[ra * 64 + (((kk * 4 + hi) ^ (lo & 7)) * 8)]);
      }
#pragma unroll
      for (int j = 0; j < 2; ++j) {
        const int rb = wn * 32 + j * 16 + lo;
        bg[kk][j] = ld8(&Bs[rb * 64 + (((kk * 4 + hi) ^ (lo & 7)) * 8)]);
      }
    }
#pragma unroll
    for (int kk = 0; kk < 2; ++kk)
#pragma unroll
      for (int mf = 0; mf < 4; ++mf)
#pragma unroll
        for (int nf = 0; nf < 2; ++nf)
          acc[mf][nf] = MFMA16(af[kk][mf], bg[kk][nf], acc[mf][nf]);
    __syncthreads();
  }

#pragma unroll
  for (int mf = 0; mf < 4; ++mf) {
#pragma unroll
    for (int rr = 0; rr < 4; ++rr) {
      const int row = m0 + wm * 64 + mf * 16 + hi * 4 + rr;
#pragma unroll
      for (int nf = 0; nf < 2; ++nf) {
        const int col = n0 + wn * 32 + nf * 16 + lo;
        out[(size_t)row * 1024 + col] = acc[mf][nf][rr] + bias[col];
      }
    }
  }
}

extern "C" void kernel_launch(void* const* d_in, const int* in_sizes, int n_in,
                              void* d_out, int out_size, void* d_ws, size_t ws_size,
                              hipStream_t stream) {
  const float* x      = (const float*)d_in[0];
  const float* Wqkv   = (const float*)d_in[1];
  const float* Wproj  = (const float*)d_in[2];
  const float* bproj  = (const float*)d_in[3];
  const float* relemb = (const float*)d_in[4];
  float* out = (float*)d_out;

  char* ws = (char*)d_ws;
  size_t off = 0;
  auto alloc = [&](size_t bytes) -> unsigned short* {
    unsigned short* p = (unsigned short*)(ws + off);
    off += (bytes + 255) & ~(size_t)255;
    return p;
  };
  unsigned short* xb  = alloc((size_t)4096 * 1024 * 2);
  unsigned short* wtq = alloc((size_t)3072 * 1024 * 2);
  unsigned short* wtp = alloc((size_t)1024 * 1024 * 2);
  unsigned short* eb  = alloc((size_t)2047 * 64 * 2);
  unsigned short* qw_ = alloc((size_t)64 * BHS * 2);
  unsigned short* kw_ = alloc((size_t)64 * BHS * 2);
  unsigned short* vtw = alloc((size_t)64 * BHS * 2);
  unsigned short* ow  = alloc((size_t)4096 * 1024 * 2);

  k_prep<<<8320, 256, 0, stream>>>(x, xb, relemb, eb, Wqkv, wtq, Wproj, wtp);
  k_gemm_qkv<<<dim3(24, 32), 256, 0, stream>>>(xb, wtq, qw_, kw_, vtw);
  k_attn<<<512, 256, 0, stream>>>(qw_, kw_, vtw, eb, ow);
  k_gemm_proj<<<dim3(16, 32), 256, 0, stream>>>(ow, wtp, bproj, out);
}